// Round 3
// baseline (15271.852 us; speedup 1.0000x reference)
//
#include <hip/hip_runtime.h>
#include <cstdint>
#include <cstddef>

// Problem constants
#define B_    256
#define T_    64
#define OBS_  4096
#define D_    1024
#define A_    8
#define H_    2048
#define ZL_   4
#define ZD_   256
#define MT_   (B_ * T_)          // 16384 rows for encoder / gi
#define EPS_  1e-5f

// ---------------------------------------------------------------------------
// Generic fp32 tiled GEMM, NT layout:  C[M,N] = A[M,K](row-major, lda)
//                                              · B[N,K](row-major, ldb)^T
// optional += bias[N], optional += Cinit[M,N] (row-major, ldci).
// Requires M%BM==0, N%BN==0, K%BK==0 (true for every shape we launch).
// ---------------------------------------------------------------------------
template <int BM, int BN, int BK, int TM, int TN>
__global__ __launch_bounds__((BM / TM) * (BN / TN))
void gemm_nt(const float* __restrict__ A, int lda,
             const float* __restrict__ Bm, int ldb,
             float* __restrict__ C, int ldc,
             int M, int N, int K,
             const float* __restrict__ bias,
             const float* __restrict__ Cinit, int ldci)
{
    constexpr int NT  = (BM / TM) * (BN / TN);   // threads per block
    constexpr int TNX = BN / TN;                 // thread-grid width (n)

    __shared__ float As[BK][BM];
    __shared__ float Bs[BK][BN];

    const int tid    = threadIdx.x;
    const int tn_idx = tid % TNX;
    const int tm_idx = tid / TNX;
    const int bm0    = blockIdx.y * BM;
    const int bn0    = blockIdx.x * BN;

    float acc[TM][TN];
#pragma unroll
    for (int i = 0; i < TM; ++i)
#pragma unroll
        for (int j = 0; j < TN; ++j) acc[i][j] = 0.f;

    for (int k0 = 0; k0 < K; k0 += BK) {
        // ---- stage A tile (transposed to As[k][m]) ----
#pragma unroll
        for (int l = tid; l < BM * BK / 4; l += NT) {
            const int row = l / (BK / 4);
            const int kq  = l % (BK / 4);
            const float4 v = *(const float4*)&A[(size_t)(bm0 + row) * lda + k0 + kq * 4];
            As[kq * 4 + 0][row] = v.x;
            As[kq * 4 + 1][row] = v.y;
            As[kq * 4 + 2][row] = v.z;
            As[kq * 4 + 3][row] = v.w;
        }
        // ---- stage B tile (transposed to Bs[k][n]) ----
#pragma unroll
        for (int l = tid; l < BN * BK / 4; l += NT) {
            const int row = l / (BK / 4);
            const int kq  = l % (BK / 4);
            const float4 v = *(const float4*)&Bm[(size_t)(bn0 + row) * ldb + k0 + kq * 4];
            Bs[kq * 4 + 0][row] = v.x;
            Bs[kq * 4 + 1][row] = v.y;
            Bs[kq * 4 + 2][row] = v.z;
            Bs[kq * 4 + 3][row] = v.w;
        }
        __syncthreads();

#pragma unroll
        for (int kk = 0; kk < BK; ++kk) {
            float a[TM], b[TN];
#pragma unroll
            for (int i = 0; i < TM; i += 4)
                *(float4*)&a[i] = *(const float4*)&As[kk][tm_idx * TM + i];
#pragma unroll
            for (int j = 0; j < TN; j += 4)
                *(float4*)&b[j] = *(const float4*)&Bs[kk][tn_idx * TN + j];
#pragma unroll
            for (int i = 0; i < TM; ++i)
#pragma unroll
                for (int j = 0; j < TN; ++j)
                    acc[i][j] = fmaf(a[i], b[j], acc[i][j]);
        }
        __syncthreads();
    }

    // ---- epilogue ----
#pragma unroll
    for (int i = 0; i < TM; ++i) {
        const int r = bm0 + tm_idx * TM + i;
#pragma unroll
        for (int j = 0; j < TN; j += 4) {
            const int c = bn0 + tn_idx * TN + j;
            float4 v = *(float4*)&acc[i][j];
            if (bias) {
                v.x += bias[c + 0]; v.y += bias[c + 1];
                v.z += bias[c + 2]; v.w += bias[c + 3];
            }
            if (Cinit) {
                const float4 ci = *(const float4*)&Cinit[(size_t)r * ldci + c];
                v.x += ci.x; v.y += ci.y; v.z += ci.z; v.w += ci.w;
            }
            *(float4*)&C[(size_t)r * ldc + c] = v;
        }
    }
}

// ---------------------------------------------------------------------------
// BatchNorm statistics: per-column sum & sum-of-squares over M rows.
// grid = (N/256, ceil(M/chunk)); accumulate privately then atomicAdd.
// ---------------------------------------------------------------------------
__global__ void bn_stats(const float* __restrict__ X, int M, int N, int chunk,
                         float* __restrict__ sum, float* __restrict__ sumsq)
{
    const int c  = blockIdx.x * blockDim.x + threadIdx.x;
    const int r0 = blockIdx.y * chunk;
    const int r1 = min(M, r0 + chunk);
    float s = 0.f, ss = 0.f;
    for (int r = r0; r < r1; ++r) {
        const float v = X[(size_t)r * N + c];
        s += v;
        ss = fmaf(v, v, ss);
    }
    atomicAdd(&sum[c], s);
    atomicAdd(&sumsq[c], ss);
}

// ---------------------------------------------------------------------------
// BatchNorm normalize (+optional ReLU); src may alias dst.
// One float4 per thread. N % 4 == 0.
// ---------------------------------------------------------------------------
__global__ void bn_norm(const float* __restrict__ src, float* __restrict__ dst,
                        int M, int N,
                        const float* __restrict__ sum, const float* __restrict__ sumsq,
                        const float* __restrict__ gamma, const float* __restrict__ beta,
                        int relu)
{
    const size_t idx = (size_t)blockIdx.x * blockDim.x + threadIdx.x;
    const size_t e0  = idx * 4;
    const int c0 = (int)(e0 % N);
    float4 v = *(const float4*)&src[e0];
    const float invM = 1.f / (float)M;
    float o[4] = {v.x, v.y, v.z, v.w};
#pragma unroll
    for (int j = 0; j < 4; ++j) {
        const int c = c0 + j;
        const float m   = sum[c] * invM;
        const float var = sumsq[c] * invM - m * m;
        float y = gamma[c] * (o[j] - m) * rsqrtf(var + EPS_) + beta[c];
        if (relu) y = fmaxf(y, 0.f);
        o[j] = y;
    }
    v.x = o[0]; v.y = o[1]; v.z = o[2]; v.w = o[3];
    *(float4*)&dst[e0] = v;
}

// ---------------------------------------------------------------------------
// Precompute action part of joint_embed for all t:
// apart[r, d] = je_b[d] + sum_k actions[r, k] * je_w[d, 1024 + k]  (r = b*T+t)
// ---------------------------------------------------------------------------
__global__ void apart_k(const float* __restrict__ act,
                        const float* __restrict__ je_w,
                        const float* __restrict__ je_b,
                        float* __restrict__ out)
{
    const size_t idx = (size_t)blockIdx.x * blockDim.x + threadIdx.x; // [16384*1024)
    const int r = (int)(idx >> 10);
    const int d = (int)(idx & 1023);
    float s = je_b[d];
    const float* wa = je_w + (size_t)d * (D_ + A_) + D_;
    const float* a  = act + (size_t)r * A_;
#pragma unroll
    for (int k = 0; k < A_; ++k) s = fmaf(a[k], wa[k], s);
    out[idx] = s;
}

// ---------------------------------------------------------------------------
// Fused GRU cell + residual:
// h[b,d] = (1-z)*n + z*hj + x_t   with gates from gi (precomputed) and gh.
// ---------------------------------------------------------------------------
__global__ void gru_cell_k(const float* __restrict__ gi,  // [MT, 3D], row b*T+t
                           const float* __restrict__ gh,  // [B, 3D]
                           const float* __restrict__ hj,  // [B, D]
                           const float* __restrict__ x,   // [MT, D]
                           float* __restrict__ h,         // [B, D] (in/out)
                           int t)
{
    const int idx = blockIdx.x * blockDim.x + threadIdx.x; // [0, 262144)
    const int b = idx >> 10;
    const int d = idx & 1023;
    const size_t gr = (size_t)b * T_ + t;

    const float* gip = gi + gr * (3 * D_);
    const float gir = gip[d], giz = gip[D_ + d], gin = gip[2 * D_ + d];
    const float* ghp = gh + (size_t)b * (3 * D_);
    const float ghr = ghp[d], ghz = ghp[D_ + d], ghn = ghp[2 * D_ + d];

    const float r = 1.f / (1.f + expf(-(gir + ghr)));
    const float z = 1.f / (1.f + expf(-(giz + ghz)));
    const float n = tanhf(fmaf(r, ghn, gin));
    const float xv = x[gr * D_ + d];
    h[idx] = (1.f - z) * n + z * hj[idx] + xv;
}

// ---------------------------------------------------------------------------
// JAX threefry2x32 (key = (0, 42)) — must match jax.random.gumbel bit-exactly.
// ---------------------------------------------------------------------------
__device__ __forceinline__ uint32_t rotl32(uint32_t x, int d)
{
    return (x << d) | (x >> (32 - d));
}

__device__ inline void threefry2x32(uint32_t k0, uint32_t k1,
                                    uint32_t& x0, uint32_t& x1)
{
    const uint32_t ks0 = k0, ks1 = k1, ks2 = k0 ^ k1 ^ 0x1BD11BDAu;
    x0 += ks0; x1 += ks1;
    const int ra[4] = {13, 15, 26, 6};
    const int rb[4] = {17, 29, 16, 24};
#pragma unroll
    for (int i = 0; i < 4; ++i) { x0 += x1; x1 = rotl32(x1, ra[i]); x1 ^= x0; }
    x0 += ks1; x1 += ks2 + 1u;
#pragma unroll
    for (int i = 0; i < 4; ++i) { x0 += x1; x1 = rotl32(x1, rb[i]); x1 ^= x0; }
    x0 += ks2; x1 += ks0 + 2u;
#pragma unroll
    for (int i = 0; i < 4; ++i) { x0 += x1; x1 = rotl32(x1, ra[i]); x1 ^= x0; }
    x0 += ks0; x1 += ks1 + 3u;
#pragma unroll
    for (int i = 0; i < 4; ++i) { x0 += x1; x1 = rotl32(x1, rb[i]); x1 ^= x0; }
    x0 += ks1; x1 += ks2 + 4u;
#pragma unroll
    for (int i = 0; i < 4; ++i) { x0 += x1; x1 = rotl32(x1, ra[i]); x1 ^= x0; }
    x0 += ks2; x1 += ks0 + 5u;
}

// ---------------------------------------------------------------------------
// Gumbel-softmax: out[0:262144] = logits (= final h), out[262144:524288] = z.
// One block per (b, zl) row of 256; one element per thread.
//
// Random bits use JAX's *partitionable* threefry scheme (default since
// JAX 0.4.36): per element i, counter = (hi32(i), lo32(i)) = (0, i) for
// i < 2^32, output bits = out_x0 ^ out_x1.  (The original scheme — iota
// split in halves, taking x0 for the first half and x1 for the second —
// produced fully decorrelated noise here: round-2 z absmax was 0.996
// while logits passed.)
// ---------------------------------------------------------------------------
__global__ void gumbel_softmax_k(const float* __restrict__ h, float* __restrict__ out)
{
    const int row = blockIdx.x;            // [0, 1024)
    const int tid = threadIdx.x;           // [0, 256)
    const int i   = row * ZD_ + tid;       // flat index into 262144
    const int lane = tid & 63;
    const int wave = tid >> 6;

    const float logit = h[i];

    // partitionable threefry bits: counter = 64-bit iota (hi=0, lo=i)
    uint32_t x0 = 0u, x1 = (uint32_t)i;
    threefry2x32(0u, 42u, x0, x1);
    const uint32_t bits = x0 ^ x1;

    // JAX uniform(minval=tiny, maxval=1) bit-twiddle, then gumbel
    const float tiny = 1.17549435e-38f;
    float f = __uint_as_float((bits >> 9) | 0x3f800000u) - 1.0f;
    f = f + tiny;
    f = fmaxf(f, tiny);
    const float g = -logf(-logf(f));

    const float val = (logit + g) / 1.0f;      // TAU = 1

    __shared__ float red[4];
    // --- max reduce over 256 threads ---
    float m = val;
#pragma unroll
    for (int o = 1; o < 64; o <<= 1) m = fmaxf(m, __shfl_xor(m, o, 64));
    if (lane == 0) red[wave] = m;
    __syncthreads();
    const float mm = fmaxf(fmaxf(red[0], red[1]), fmaxf(red[2], red[3]));
    __syncthreads();

    const float e = expf(val - mm);
    float s = e;
#pragma unroll
    for (int o = 1; o < 64; o <<= 1) s += __shfl_xor(s, o, 64);
    if (lane == 0) red[wave] = s;
    __syncthreads();
    const float ssum = red[0] + red[1] + red[2] + red[3];

    out[i] = logit;                              // logits
    out[B_ * ZL_ * ZD_ + i] = e / ssum;          // z
}

// ---------------------------------------------------------------------------
// Host-side launch
// ---------------------------------------------------------------------------
extern "C" void kernel_launch(void* const* d_in, const int* in_sizes, int n_in,
                              void* d_out, int out_size, void* d_ws, size_t ws_size,
                              hipStream_t stream)
{
    const float* obs      = (const float*)d_in[0];
    const float* actions  = (const float*)d_in[1];
    const float* enc_w1   = (const float*)d_in[2];
    // d_in[3] = enc_b1  (cancels in BN)
    const float* enc_g1   = (const float*)d_in[4];
    const float* enc_bt1  = (const float*)d_in[5];
    const float* enc_w2   = (const float*)d_in[6];
    // d_in[7] = enc_b2  (cancels in BN)
    const float* enc_g2   = (const float*)d_in[8];
    const float* enc_bt2  = (const float*)d_in[9];
    const float* je_w     = (const float*)d_in[10];
    const float* je_b     = (const float*)d_in[11];
    const float* gru_wih  = (const float*)d_in[12];
    const float* gru_bih  = (const float*)d_in[13];
    const float* gru_whh  = (const float*)d_in[14];
    const float* gru_bhh  = (const float*)d_in[15];
    const float* dec_w1   = (const float*)d_in[16];
    // d_in[17] = dec_b1 (cancels in BN)
    const float* dec_g1   = (const float*)d_in[18];
    const float* dec_bt1  = (const float*)d_in[19];
    const float* dec_w2   = (const float*)d_in[20];
    // d_in[21] = dec_b2 (cancels in BN)
    const float* dec_g2   = (const float*)d_in[22];
    const float* dec_bt2  = (const float*)d_in[23];

    float* out = (float*)d_out;

    // ---- workspace layout (floats), ~344 MB total ----
    float* W = (float*)d_ws;
    float* c1    = W;                          // [16384, 2048]  (128 MB) — dead after enc GEMM2
    float* gi    = W;                          // [16384, 3072]  (192 MB) — reuses c1's region
    float* xbuf  = W + (size_t)50331648;       // [16384, 1024]  (64 MB)
    float* apart = xbuf + (size_t)16777216;    // [16384, 1024]  (64 MB)
    float* h     = apart + (size_t)16777216;   // [256, 1024]
    float* hjb   = h + 262144;                 // [256, 1024]
    float* ghb   = hjb + 262144;               // [256, 3072]
    float* ssum  = ghb + 786432;               // [4096]
    float* ssq   = ssum + 4096;                // [4096]
    float* d1    = ssq + 4096;                 // [256, 2048]

    // ================= encoder =================
    // GEMM1: c1 = obs @ enc_w1^T      [16384, 2048]
    gemm_nt<128, 128, 16, 8, 8><<<dim3(2048 / 128, 16384 / 128), 256, 0, stream>>>(
        obs, OBS_, enc_w1, OBS_, c1, H_, MT_, H_, OBS_, nullptr, nullptr, 0);
    // BN(relu) over 16384 rows
    hipMemsetAsync(ssum, 0, 8192 * sizeof(float), stream);
    bn_stats<<<dim3(H_ / 256, MT_ / 512), 256, 0, stream>>>(c1, MT_, H_, 512, ssum, ssq);
    bn_norm<<<(size_t)MT_ * H_ / 1024, 256, 0, stream>>>(c1, c1, MT_, H_, ssum, ssq,
                                                         enc_g1, enc_bt1, 1);
    // GEMM2: xbuf = c1 @ enc_w2^T    [16384, 1024]
    gemm_nt<128, 128, 16, 8, 8><<<dim3(D_ / 128, 16384 / 128), 256, 0, stream>>>(
        c1, H_, enc_w2, H_, xbuf, D_, MT_, D_, H_, nullptr, nullptr, 0);
    hipMemsetAsync(ssum, 0, 8192 * sizeof(float), stream);
    bn_stats<<<dim3(D_ / 256, MT_ / 512), 256, 0, stream>>>(xbuf, MT_, D_, 512, ssum, ssq);
    bn_norm<<<(size_t)MT_ * D_ / 1024, 256, 0, stream>>>(xbuf, xbuf, MT_, D_, ssum, ssq,
                                                         enc_g2, enc_bt2, 0);

    // ================= hoisted scan-invariant GEMMs =================
    // gi = xbuf @ gru_wih^T + bih    [16384, 3072]   (c1 region now dead -> gi)
    gemm_nt<128, 128, 16, 8, 8><<<dim3(3072 / 128, 16384 / 128), 256, 0, stream>>>(
        xbuf, D_, gru_wih, D_, gi, 3 * D_, MT_, 3 * D_, D_, gru_bih, nullptr, 0);
    // apart[r,d] = je_b[d] + actions[r,:] @ je_w[d, 1024:]
    apart_k<<<(size_t)MT_ * D_ / 256, 256, 0, stream>>>(actions, je_w, je_b, apart);

    // ================= recurrent scan =================
    hipMemsetAsync(h, 0, 262144 * sizeof(float), stream);
    for (int t = 0; t < T_; ++t) {
        // hj = h @ je_w[:, :1024]^T + apart[:, t, :]
        gemm_nt<64, 64, 16, 4, 4><<<dim3(D_ / 64, B_ / 64), 256, 0, stream>>>(
            h, D_, je_w, D_ + A_, hjb, D_, B_, D_, D_,
            nullptr, apart + (size_t)t * D_, T_ * D_);
        // gh = hj @ gru_whh^T + bhh
        gemm_nt<64, 64, 16, 4, 4><<<dim3(3 * D_ / 64, B_ / 64), 256, 0, stream>>>(
            hjb, D_, gru_whh, D_, ghb, 3 * D_, B_, 3 * D_, D_,
            gru_bhh, nullptr, 0);
        // fused GRU cell + residual
        gru_cell_k<<<(B_ * D_) / 256, 256, 0, stream>>>(gi, ghb, hjb, xbuf, h, t);
    }

    // ================= gumbel softmax =================
    gumbel_softmax_k<<<B_ * ZL_, ZD_, 0, stream>>>(h, out);

    // ================= decoder =================
    const float* zmat = out + (size_t)B_ * ZL_ * ZD_;   // z, [256, 1024]
    float* xhat = out + (size_t)2 * B_ * ZL_ * ZD_;     // [256, 4096]
    // dec GEMM1: d1 = z @ dec_w1^T   [256, 2048]
    gemm_nt<64, 64, 16, 4, 4><<<dim3(H_ / 64, B_ / 64), 256, 0, stream>>>(
        zmat, D_, dec_w1, D_, d1, H_, B_, H_, D_, nullptr, nullptr, 0);
    hipMemsetAsync(ssum, 0, 8192 * sizeof(float), stream);
    bn_stats<<<dim3(H_ / 256, 1), 256, 0, stream>>>(d1, B_, H_, B_, ssum, ssq);
    bn_norm<<<(size_t)B_ * H_ / 1024, 256, 0, stream>>>(d1, d1, B_, H_, ssum, ssq,
                                                        dec_g1, dec_bt1, 1);
    // dec GEMM2: xhat = d1 @ dec_w2^T  [256, 4096]
    gemm_nt<64, 64, 16, 4, 4><<<dim3(OBS_ / 64, B_ / 64), 256, 0, stream>>>(
        d1, H_, dec_w2, H_, xhat, OBS_, B_, OBS_, H_, nullptr, nullptr, 0);
    hipMemsetAsync(ssum, 0, 8192 * sizeof(float), stream);
    bn_stats<<<dim3(OBS_ / 256, 1), 256, 0, stream>>>(xhat, B_, OBS_, B_, ssum, ssq);
    bn_norm<<<(size_t)B_ * OBS_ / 1024, 256, 0, stream>>>(xhat, xhat, B_, OBS_, ssum, ssq,
                                                          dec_g2, dec_bt2, 0);
}

// Round 5
// 8375.249 us; speedup vs baseline: 1.8235x; 1.8235x over previous
//
#include <hip/hip_runtime.h>
#include <cstdint>
#include <cstddef>

// Problem constants
#define B_    256
#define T_    64
#define OBS_  4096
#define D_    1024
#define A_    8
#define H_    2048
#define ZL_   4
#define ZD_   256
#define MT_   (B_ * T_)
#define EPS_  1e-5f

typedef unsigned short u16;
typedef __attribute__((ext_vector_type(8))) short short8v;   // 8 bf16 in 4 VGPRs
typedef __attribute__((ext_vector_type(4))) float float4v;   // MFMA accumulator

__device__ __forceinline__ u16 f2bf(float f) {               // RNE f32->bf16
    uint32_t u = __float_as_uint(f);
    return (u16)((u + 0x7FFFu + ((u >> 16) & 1u)) >> 16);
}
__device__ __forceinline__ float bf2f(u16 h) {
    return __uint_as_float(((uint32_t)h) << 16);
}

// async global->LDS, 16B per lane. LDS base must be wave-uniform; HW writes
// base + lane*16. Global src is per-lane.
__device__ __forceinline__ void async_cp16(const void* g, void* l) {
    __builtin_amdgcn_global_load_lds(
        (const __attribute__((address_space(1))) void*)g,
        (__attribute__((address_space(3))) void*)l, 16, 0, 0);
}

// ---------------------------------------------------------------------------
// bf16 MFMA GEMM, NT: C[M,N] = A[M,K](bf16,row-major,lda) . B[N,K](bf16)^T
// fp32 accumulate. Optional +bias[N](f32), +Cinit(bf16, ldci elements).
// Output: Cf (f32) and/or Cb (bf16), both nullable, same ldc.
// Tile 128x128, BK=32, 4 waves (2x2), each wave 4x4 16x16x32 fragments.
// M%128==0, N%128==0, K%32==0, lda/ldb/ldc %8==0 required.
// ---------------------------------------------------------------------------
__global__ __launch_bounds__(256)
void mfma_gemm_nt(const u16* __restrict__ A, int lda,
                  const u16* __restrict__ Bm, int ldb,
                  float* __restrict__ Cf, u16* __restrict__ Cb, int ldc,
                  int M, int N, int K,
                  const float* __restrict__ bias,
                  const u16* __restrict__ Cinit, long ldci)
{
    __shared__ u16 As[128 * 32];
    __shared__ u16 Bs[128 * 32];

    const int tid  = threadIdx.x;
    const int lane = tid & 63;
    const int w    = tid >> 6;         // wave 0..3
    const int wm   = w >> 1;           // wave row (0..1)
    const int wn   = w & 1;            // wave col (0..1)
    const int bm0  = blockIdx.y * 128;
    const int bn0  = blockIdx.x * 128;

    float4v acc[4][4];
#pragma unroll
    for (int i = 0; i < 4; ++i)
#pragma unroll
        for (int j = 0; j < 4; ++j)
            acc[i][j] = (float4v){0.f, 0.f, 0.f, 0.f};

    // staging: chunk q of wave w covers tile rows (w*2+q)*16 + lane/4,
    // k-slice (lane%4)*8. LDS linear layout As[tile_row*32 + k_off].
    const int srow = lane >> 2;
    const int skel = (lane & 3) * 8;
    const int r0t  = (w * 2 + 0) * 16 + srow;
    const int r1t  = (w * 2 + 1) * 16 + srow;

    const int fr = lane & 15;          // fragment row within 16
    const int fo = (lane >> 4) * 8;    // fragment k offset (8 elems)

    for (int k0 = 0; k0 < K; k0 += 32) {
        async_cp16(A  + (size_t)(bm0 + r0t) * lda + k0 + skel, &As[(w * 2 + 0) * 512]);
        async_cp16(A  + (size_t)(bm0 + r1t) * lda + k0 + skel, &As[(w * 2 + 1) * 512]);
        async_cp16(Bm + (size_t)(bn0 + r0t) * ldb + k0 + skel, &Bs[(w * 2 + 0) * 512]);
        async_cp16(Bm + (size_t)(bn0 + r1t) * ldb + k0 + skel, &Bs[(w * 2 + 1) * 512]);
        __syncthreads();   // compiler drains vmcnt before s_barrier

        short8v fa[4], fb[4];
#pragma unroll
        for (int i = 0; i < 4; ++i) {
            fa[i] = *(const short8v*)&As[(wm * 64 + i * 16 + fr) * 32 + fo];
            fb[i] = *(const short8v*)&Bs[(wn * 64 + i * 16 + fr) * 32 + fo];
        }
#pragma unroll
        for (int i = 0; i < 4; ++i)
#pragma unroll
            for (int j = 0; j < 4; ++j)
                acc[i][j] = __builtin_amdgcn_mfma_f32_16x16x32_bf16(fa[i], fb[j], acc[i][j], 0, 0, 0);
        __syncthreads();
    }

    // epilogue: C/D layout col = lane&15, row = (lane>>4)*4 + reg (m89-verified)
    const int cr = (lane >> 4) * 4;
    const int cc = lane & 15;
#pragma unroll
    for (int i = 0; i < 4; ++i) {
#pragma unroll
        for (int j = 0; j < 4; ++j) {
#pragma unroll
            for (int r = 0; r < 4; ++r) {
                const int row = bm0 + wm * 64 + i * 16 + cr + r;
                const int col = bn0 + wn * 64 + j * 16 + cc;
                float v = acc[i][j][r];
                if (bias)  v += bias[col];
                if (Cinit) v += bf2f(Cinit[(size_t)row * ldci + col]);
                if (Cf) Cf[(size_t)row * ldc + col] = v;
                if (Cb) Cb[(size_t)row * ldc + col] = f2bf(v);
            }
        }
    }
}

// ---------------------------------------------------------------------------
// fp32 tiled GEMM (NT) — decoder GEMMs + exact Wpre = whh . Wje.
// ---------------------------------------------------------------------------
template <int BM, int BN, int BK, int TM, int TN>
__global__ __launch_bounds__((BM / TM) * (BN / TN))
void gemm_nt(const float* __restrict__ A, int lda,
             const float* __restrict__ Bm, int ldb,
             float* __restrict__ C, int ldc,
             int M, int N, int K,
             const float* __restrict__ bias,
             const float* __restrict__ Cinit, int ldci)
{
    constexpr int NT  = (BM / TM) * (BN / TN);
    constexpr int TNX = BN / TN;
    __shared__ float As[BK][BM];
    __shared__ float Bs[BK][BN];
    const int tid = threadIdx.x;
    const int tn_idx = tid % TNX;
    const int tm_idx = tid / TNX;
    const int bm0 = blockIdx.y * BM;
    const int bn0 = blockIdx.x * BN;

    float acc[TM][TN];
#pragma unroll
    for (int i = 0; i < TM; ++i)
#pragma unroll
        for (int j = 0; j < TN; ++j) acc[i][j] = 0.f;

    for (int k0 = 0; k0 < K; k0 += BK) {
#pragma unroll
        for (int l = tid; l < BM * BK / 4; l += NT) {
            const int row = l / (BK / 4);
            const int kq  = l % (BK / 4);
            const float4 v = *(const float4*)&A[(size_t)(bm0 + row) * lda + k0 + kq * 4];
            As[kq * 4 + 0][row] = v.x; As[kq * 4 + 1][row] = v.y;
            As[kq * 4 + 2][row] = v.z; As[kq * 4 + 3][row] = v.w;
        }
#pragma unroll
        for (int l = tid; l < BN * BK / 4; l += NT) {
            const int row = l / (BK / 4);
            const int kq  = l % (BK / 4);
            const float4 v = *(const float4*)&Bm[(size_t)(bn0 + row) * ldb + k0 + kq * 4];
            Bs[kq * 4 + 0][row] = v.x; Bs[kq * 4 + 1][row] = v.y;
            Bs[kq * 4 + 2][row] = v.z; Bs[kq * 4 + 3][row] = v.w;
        }
        __syncthreads();
#pragma unroll
        for (int kk = 0; kk < BK; ++kk) {
            float a[TM], b[TN];
#pragma unroll
            for (int i = 0; i < TM; i += 4)
                *(float4*)&a[i] = *(const float4*)&As[kk][tm_idx * TM + i];
#pragma unroll
            for (int j = 0; j < TN; j += 4)
                *(float4*)&b[j] = *(const float4*)&Bs[kk][tn_idx * TN + j];
#pragma unroll
            for (int i = 0; i < TM; ++i)
#pragma unroll
                for (int j = 0; j < TN; ++j)
                    acc[i][j] = fmaf(a[i], b[j], acc[i][j]);
        }
        __syncthreads();
    }
#pragma unroll
    for (int i = 0; i < TM; ++i) {
        const int r = bm0 + tm_idx * TM + i;
#pragma unroll
        for (int j = 0; j < TN; j += 4) {
            const int c = bn0 + tn_idx * TN + j;
            float4 v = *(float4*)&acc[i][j];
            if (bias) { v.x += bias[c]; v.y += bias[c+1]; v.z += bias[c+2]; v.w += bias[c+3]; }
            if (Cinit) {
                const float4 ci = *(const float4*)&Cinit[(size_t)r * ldci + c];
                v.x += ci.x; v.y += ci.y; v.z += ci.z; v.w += ci.w;
            }
            *(float4*)&C[(size_t)r * ldc + c] = v;
        }
    }
}

// ---------------------------------------------------------------------------
// fp32 -> bf16 cast, 2D (8 elems/thread). C%8==0, sld/dld element strides.
// ---------------------------------------------------------------------------
__global__ void cast2d_k(const float* __restrict__ src, int sld,
                         u16* __restrict__ dst, int dld, long total, int C)
{
    long i = ((long)blockIdx.x * blockDim.x + threadIdx.x) * 8;
    if (i >= total) return;
    const int r = (int)(i / C);
    const int c = (int)(i % C);
    const float* s = src + (size_t)r * sld + c;
    const float4 a = *(const float4*)s;
    const float4 b = *(const float4*)(s + 4);
    uint4 o;
    o.x = (uint32_t)f2bf(a.x) | ((uint32_t)f2bf(a.y) << 16);
    o.y = (uint32_t)f2bf(a.z) | ((uint32_t)f2bf(a.w) << 16);
    o.z = (uint32_t)f2bf(b.x) | ((uint32_t)f2bf(b.y) << 16);
    o.w = (uint32_t)f2bf(b.z) | ((uint32_t)f2bf(b.w) << 16);
    *(uint4*)&dst[(size_t)r * dld + c] = o;
}

// f32 transpose (1024x1024 block-covered): dst[c][r] = src[r][c]
__global__ void trans_f32_k(const float* __restrict__ src, int sld,
                            float* __restrict__ dst, int dld)
{
    __shared__ float t[32][33];
    const int c0 = blockIdx.x * 32, r0 = blockIdx.y * 32;
    for (int dy = threadIdx.y; dy < 32; dy += 8)
        t[dy][threadIdx.x] = src[(size_t)(r0 + dy) * sld + c0 + threadIdx.x];
    __syncthreads();
    for (int dy = threadIdx.y; dy < 32; dy += 8)
        dst[(size_t)(c0 + dy) * dld + r0 + threadIdx.x] = t[threadIdx.x][dy];
}

// split-cast into scan weight triple: dst row r gets [hi | hi | lo] (1024 each)
__global__ void cast_split3_k(const float* __restrict__ src, int sld,
                              u16* __restrict__ dst, long total)
{
    long idx = (long)blockIdx.x * blockDim.x + threadIdx.x;
    if (idx >= total) return;
    const int r = (int)(idx >> 10);
    const int c = (int)(idx & 1023);
    const float w = src[(size_t)r * sld + c];
    const u16 hi = f2bf(w);
    const u16 lo = f2bf(w - bf2f(hi));
    u16* dp = dst + (size_t)r * 3072;
    dp[c] = hi; dp[1024 + c] = hi; dp[2048 + c] = lo;
}

// ---------------------------------------------------------------------------
// BatchNorm stats (f32 and bf16 input variants) + normalize variants
// ---------------------------------------------------------------------------
__global__ void bn_stats(const float* __restrict__ X, int M, int N, int chunk,
                         float* __restrict__ sum, float* __restrict__ sumsq)
{
    const int c  = blockIdx.x * blockDim.x + threadIdx.x;
    const int r0 = blockIdx.y * chunk;
    const int r1 = min(M, r0 + chunk);
    float s = 0.f, ss = 0.f;
    for (int r = r0; r < r1; ++r) {
        const float v = X[(size_t)r * N + c];
        s += v; ss = fmaf(v, v, ss);
    }
    atomicAdd(&sum[c], s);
    atomicAdd(&sumsq[c], ss);
}

__global__ void bn_stats_bf(const u16* __restrict__ X, int M, int N, int chunk,
                            float* __restrict__ sum, float* __restrict__ sumsq)
{
    const int c  = blockIdx.x * blockDim.x + threadIdx.x;
    const int r0 = blockIdx.y * chunk;
    const int r1 = min(M, r0 + chunk);
    float s = 0.f, ss = 0.f;
    for (int r = r0; r < r1; ++r) {
        const float v = bf2f(X[(size_t)r * N + c]);
        s += v; ss = fmaf(v, v, ss);
    }
    atomicAdd(&sum[c], s);
    atomicAdd(&sumsq[c], ss);
}

// bf16 in -> bf16 out (src may alias dst); 8 elems/thread, N%8==0
__global__ void bn_norm_bf(const u16* __restrict__ src, u16* __restrict__ dst,
                           int M, int N,
                           const float* __restrict__ sum, const float* __restrict__ sumsq,
                           const float* __restrict__ gamma, const float* __restrict__ beta,
                           int relu)
{
    const size_t idx = (size_t)blockIdx.x * blockDim.x + threadIdx.x;
    const size_t e0  = idx * 8;
    const int c0 = (int)(e0 % N);
    const uint4 v = *(const uint4*)&src[e0];
    const u16* pv = (const u16*)&v;
    const float invM = 1.f / (float)M;
    u16 o[8];
#pragma unroll
    for (int j = 0; j < 8; ++j) {
        const int c = c0 + j;
        const float m   = sum[c] * invM;
        const float var = sumsq[c] * invM - m * m;
        float y = gamma[c] * (bf2f(pv[j]) - m) * rsqrtf(var + EPS_) + beta[c];
        if (relu) y = fmaxf(y, 0.f);
        o[j] = f2bf(y);
    }
    *(uint4*)&dst[e0] = *(uint4*)o;
}

// f32 in -> f32 out (decoder)
__global__ void bn_norm_f(const float* __restrict__ src, float* __restrict__ dst,
                          int M, int N,
                          const float* __restrict__ sum, const float* __restrict__ sumsq,
                          const float* __restrict__ gamma, const float* __restrict__ beta,
                          int relu)
{
    const size_t idx = (size_t)blockIdx.x * blockDim.x + threadIdx.x;
    const size_t e0  = idx * 4;
    const int c0 = (int)(e0 % N);
    const float4 v = *(const float4*)&src[e0];
    const float invM = 1.f / (float)M;
    float o[4] = {v.x, v.y, v.z, v.w};
#pragma unroll
    for (int j = 0; j < 4; ++j) {
        const int c = c0 + j;
        const float m   = sum[c] * invM;
        const float var = sumsq[c] * invM - m * m;
        float y = gamma[c] * (o[j] - m) * rsqrtf(var + EPS_) + beta[c];
        if (relu) y = fmaxf(y, 0.f);
        o[j] = y;
    }
    float4 w = {o[0], o[1], o[2], o[3]};
    *(float4*)&dst[e0] = w;
}

// ---------------------------------------------------------------------------
// ap into addcat cols 0..1023 (row stride 4096):
// addcat[r, d] = bf16( je_b[d] + sum_k actions[r,k]*je_w[d,1024+k] )
// ---------------------------------------------------------------------------
__global__ void apart_k(const float* __restrict__ act,
                        const float* __restrict__ je_w,
                        const float* __restrict__ je_b,
                        u16* __restrict__ addcat)
{
    const size_t idx = (size_t)blockIdx.x * blockDim.x + threadIdx.x;
    const int r = (int)(idx >> 10);
    const int d = (int)(idx & 1023);
    float s = je_b[d];
    const float* wa = je_w + (size_t)d * (D_ + A_) + D_;
    const float* a  = act + (size_t)r * A_;
#pragma unroll
    for (int k = 0; k < A_; ++k) s = fmaf(a[k], wa[k], s);
    addcat[(size_t)r * 4096 + d] = f2bf(s);
}

// ---------------------------------------------------------------------------
// GRU cell + residual. mstep row b: [hj | ghr | ghz | ghn] (f32).
// Writes hf (f32) and the split triple hsplit3[b] = [h_hi | h_lo | h_hi].
// ---------------------------------------------------------------------------
__global__ void gru_cell3(const float* __restrict__ mstep,
                          const u16* __restrict__ gi,     // bf16 [MT,3072]
                          const u16* __restrict__ x,      // bf16 [MT,1024]
                          float* __restrict__ hf,         // f32 [256,1024]
                          u16* __restrict__ hsplit3,      // bf16 [256,3072]
                          int t)
{
    const int idx = blockIdx.x * blockDim.x + threadIdx.x; // [0, 262144)
    const int b = idx >> 10;
    const int d = idx & 1023;
    const float* mp = mstep + (size_t)b * 4096;
    const float hj  = mp[d];
    const float ghr = mp[1024 + d], ghz = mp[2048 + d], ghn = mp[3072 + d];
    const size_t r = (size_t)b * T_ + t;
    const u16* gp = gi + r * 3072;
    const float gir = bf2f(gp[d]), giz = bf2f(gp[1024 + d]), gin = bf2f(gp[2048 + d]);

    const float rr = 1.f / (1.f + expf(-(gir + ghr)));
    const float zz = 1.f / (1.f + expf(-(giz + ghz)));
    const float nn = tanhf(fmaf(rr, ghn, gin));
    const float h  = (1.f - zz) * nn + zz * hj + bf2f(x[r * 1024 + d]);

    hf[idx] = h;
    const u16 hi = f2bf(h);
    const u16 lo = f2bf(h - bf2f(hi));
    u16* hp = hsplit3 + (size_t)b * 3072;
    hp[d] = hi; hp[1024 + d] = lo; hp[2048 + d] = hi;
}

// ---------------------------------------------------------------------------
// JAX threefry2x32 (key=(0,42)), partitionable scheme — validated round 3.
// ---------------------------------------------------------------------------
__device__ __forceinline__ uint32_t rotl32(uint32_t x, int d)
{
    return (x << d) | (x >> (32 - d));
}

__device__ inline void threefry2x32(uint32_t k0, uint32_t k1,
                                    uint32_t& x0, uint32_t& x1)
{
    const uint32_t ks0 = k0, ks1 = k1, ks2 = k0 ^ k1 ^ 0x1BD11BDAu;
    x0 += ks0; x1 += ks1;
    const int ra[4] = {13, 15, 26, 6};
    const int rb[4] = {17, 29, 16, 24};
#pragma unroll
    for (int i = 0; i < 4; ++i) { x0 += x1; x1 = rotl32(x1, ra[i]); x1 ^= x0; }
    x0 += ks1; x1 += ks2 + 1u;
#pragma unroll
    for (int i = 0; i < 4; ++i) { x0 += x1; x1 = rotl32(x1, rb[i]); x1 ^= x0; }
    x0 += ks2; x1 += ks0 + 2u;
#pragma unroll
    for (int i = 0; i < 4; ++i) { x0 += x1; x1 = rotl32(x1, ra[i]); x1 ^= x0; }
    x0 += ks0; x1 += ks1 + 3u;
#pragma unroll
    for (int i = 0; i < 4; ++i) { x0 += x1; x1 = rotl32(x1, rb[i]); x1 ^= x0; }
    x0 += ks1; x1 += ks2 + 4u;
#pragma unroll
    for (int i = 0; i < 4; ++i) { x0 += x1; x1 = rotl32(x1, ra[i]); x1 ^= x0; }
    x0 += ks2; x1 += ks0 + 5u;
}

__global__ void gumbel_softmax_k(const float* __restrict__ h, float* __restrict__ out)
{
    const int row = blockIdx.x;
    const int tid = threadIdx.x;
    const int i   = row * ZD_ + tid;
    const int lane = tid & 63;
    const int wave = tid >> 6;

    const float logit = h[i];

    uint32_t x0 = 0u, x1 = (uint32_t)i;
    threefry2x32(0u, 42u, x0, x1);
    const uint32_t bits = x0 ^ x1;

    const float tiny = 1.17549435e-38f;
    float f = __uint_as_float((bits >> 9) | 0x3f800000u) - 1.0f;
    f = f + tiny;
    f = fmaxf(f, tiny);
    const float g = -logf(-logf(f));

    const float val = (logit + g) / 1.0f;

    __shared__ float red[4];
    float m = val;
#pragma unroll
    for (int o = 1; o < 64; o <<= 1) m = fmaxf(m, __shfl_xor(m, o, 64));
    if (lane == 0) red[wave] = m;
    __syncthreads();
    const float mm = fmaxf(fmaxf(red[0], red[1]), fmaxf(red[2], red[3]));
    __syncthreads();

    const float e = expf(val - mm);
    float s = e;
#pragma unroll
    for (int o = 1; o < 64; o <<= 1) s += __shfl_xor(s, o, 64);
    if (lane == 0) red[wave] = s;
    __syncthreads();
    const float ssum = red[0] + red[1] + red[2] + red[3];

    out[i] = logit;
    out[B_ * ZL_ * ZD_ + i] = e / ssum;
}

// ---------------------------------------------------------------------------
// Host-side launch
// ---------------------------------------------------------------------------
extern "C" void kernel_launch(void* const* d_in, const int* in_sizes, int n_in,
                              void* d_out, int out_size, void* d_ws, size_t ws_size,
                              hipStream_t stream)
{
    const float* obs      = (const float*)d_in[0];
    const float* actions  = (const float*)d_in[1];
    const float* enc_w1   = (const float*)d_in[2];
    const float* enc_g1   = (const float*)d_in[4];
    const float* enc_bt1  = (const float*)d_in[5];
    const float* enc_w2   = (const float*)d_in[6];
    const float* enc_g2   = (const float*)d_in[8];
    const float* enc_bt2  = (const float*)d_in[9];
    const float* je_w     = (const float*)d_in[10];
    const float* je_b     = (const float*)d_in[11];
    const float* gru_wih  = (const float*)d_in[12];
    const float* gru_bih  = (const float*)d_in[13];
    const float* gru_whh  = (const float*)d_in[14];
    const float* gru_bhh  = (const float*)d_in[15];
    const float* dec_w1   = (const float*)d_in[16];
    const float* dec_g1   = (const float*)d_in[18];
    const float* dec_bt1  = (const float*)d_in[19];
    const float* dec_w2   = (const float*)d_in[20];
    const float* dec_g2   = (const float*)d_in[22];
    const float* dec_bt2  = (const float*)d_in[23];

    float* out = (float*)d_out;

    // ---- workspace layout (~326 MB total; proven bound is 344 MB) ----
    char* P = (char*)d_ws;
    // slab0 [0, 128MB): obs_bf [16384,4096]bf16  ->  addcat [16384,4096]bf16
    u16* obs_bf = (u16*)P;
    u16* addcat = (u16*)P;
    // slab1 [128, 224MB): c2b [16384,1024]bf16 (enc2 out) -> gi_bf [16384,3072]bf16
    u16* c2b   = (u16*)(P + 134217728);
    u16* gi_bf = (u16*)(P + 134217728);
    // slab2 [224, 288MB): c1b [16384,2048]bf16 (enc1) -> {xbuf_bf, mstep, hf, d1, wpreF}
    char* slab2 = P + 234881024;
    u16*   c1b     = (u16*)slab2;                     // 64 MB, dead after enc2
    u16*   xbuf_bf = (u16*)slab2;                     // [0,32MB): x bf16 [16384,1024]
    float* mstep   = (float*)(slab2 + 33554432);      // [32,36MB): [256,4096] f32
    float* hf      = (float*)(slab2 + 37748736);      // [36,37MB): [256,1024] f32
    float* d1      = (float*)(slab2 + 38797312);      // [37,39MB): [256,2048] f32
    float* wpreF   = (float*)(slab2 + 41943040);      // [40,52MB): [3072,1024] f32, pre-scan
    // weights [288MB, ...): pool w1b/w2b/wihb is overlaid by wcat3 after gi
    char* wp = P + 301989888;
    u16*  w1b   = (u16*)wp;                 // 16 MB  [2048,4096]
    u16*  w2b   = (u16*)(wp + 16777216);    // 4 MB   [1024,2048]
    u16*  wihb  = (u16*)(wp + 20971520);    // 6 MB   [3072,1024]
    u16*  wcat3 = (u16*)wp;                 // 24 MB  [4096,3072] overlays w1b/w2b/wihb
    u16*  whhb  = (u16*)(wp + 27262976);    // 6 MB   [3072,1024]
    float* wjetf = (float*)(wp + 33554432); // 4 MB   [1024,1024] f32 (Wje^T)
    float* ssum  = (float*)(wp + 37748736); // 16 KB
    float* ssq   = (float*)(wp + 37765120); // 16 KB
    u16*  hsplit3 = (u16*)(wp + 37781504);  // 1.5 MB [256,3072]

    // ================= casts =================
    cast2d_k<<<32768, 256, 0, stream>>>(obs,     4096, obs_bf, 4096, (long)MT_ * OBS_, OBS_);
    cast2d_k<<<4096,  256, 0, stream>>>(enc_w1,  4096, w1b,    4096, (long)H_ * OBS_,  OBS_);
    cast2d_k<<<1024,  256, 0, stream>>>(enc_w2,  2048, w2b,    2048, (long)D_ * H_,    H_);
    cast2d_k<<<1536,  256, 0, stream>>>(gru_wih, 1024, wihb,   1024, (long)3 * D_ * D_, D_);
    cast2d_k<<<1536,  256, 0, stream>>>(gru_whh, 1024, whhb,   1024, (long)3 * D_ * D_, D_);
    trans_f32_k<<<dim3(32, 32), dim3(32, 8), 0, stream>>>(je_w, D_ + A_, wjetf, D_);

    // ================= encoder (bf16 MFMA; BN stats on bf16 pre-act) ========
    mfma_gemm_nt<<<dim3(H_ / 128, MT_ / 128), 256, 0, stream>>>(
        obs_bf, OBS_, w1b, OBS_, nullptr, c1b, H_, MT_, H_, OBS_, nullptr, nullptr, 0);
    hipMemsetAsync(ssum, 0, 32768, stream);
    bn_stats_bf<<<dim3(H_ / 256, MT_ / 512), 256, 0, stream>>>(c1b, MT_, H_, 512, ssum, ssq);
    bn_norm_bf<<<(size_t)MT_ * H_ / 2048, 256, 0, stream>>>(c1b, c1b, MT_, H_,
                                                            ssum, ssq, enc_g1, enc_bt1, 1);
    mfma_gemm_nt<<<dim3(D_ / 128, MT_ / 128), 256, 0, stream>>>(
        c1b, H_, w2b, H_, nullptr, c2b, D_, MT_, D_, H_, nullptr, nullptr, 0);
    hipMemsetAsync(ssum, 0, 32768, stream);
    bn_stats_bf<<<dim3(D_ / 256, MT_ / 512), 256, 0, stream>>>(c2b, MT_, D_, 512, ssum, ssq);
    bn_norm_bf<<<(size_t)MT_ * D_ / 2048, 256, 0, stream>>>(c2b, xbuf_bf, MT_, D_,
                                                            ssum, ssq, enc_g2, enc_bt2, 0);

    // ================= gi (scan-invariant input gates) =================
    mfma_gemm_nt<<<dim3(3 * D_ / 128, MT_ / 128), 256, 0, stream>>>(
        xbuf_bf, D_, wihb, D_, nullptr, gi_bf, 3 * D_, MT_, 3 * D_, D_,
        gru_bih, nullptr, 0);

    // ================= scan prep =================
    // ap -> addcat cols 0..1023
    apart_k<<<(size_t)MT_ * D_ / 256, 256, 0, stream>>>(actions, je_w, je_b, addcat);
    // apw = ap @ whh^T + bhh -> addcat cols 1024..4095
    mfma_gemm_nt<<<dim3(3 * D_ / 128, MT_ / 128), 256, 0, stream>>>(
        addcat, 4096, whhb, D_, nullptr, addcat + 1024, 4096, MT_, 3 * D_, D_,
        gru_bhh, nullptr, 0);
    // Wpre = whh . Wje (exact fp32)
    gemm_nt<64, 64, 16, 4, 4><<<dim3(D_ / 64, 3 * D_ / 64), 256, 0, stream>>>(
        gru_whh, D_, wjetf, D_, wpreF, D_, 3 * D_, D_, D_, nullptr, nullptr, 0);
    // wcat3 rows 0..1023 = split(Wje), rows 1024..4095 = split(Wpre)
    cast_split3_k<<<4096, 256, 0, stream>>>(je_w, D_ + A_, wcat3, (long)D_ * D_);
    cast_split3_k<<<12288, 256, 0, stream>>>(wpreF, D_, wcat3 + (size_t)1024 * 3072,
                                             (long)3 * D_ * D_);

    // ================= recurrent scan =================
    hipMemsetAsync(hsplit3, 0, (size_t)B_ * 3072 * 2, stream);
    for (int t = 0; t < T_; ++t) {
        // mstep = [h_hi|h_lo|h_hi] @ [Whi|Whi|Wlo]^T + addcat_t  (hj|ghr|ghz|ghn)
        mfma_gemm_nt<<<dim3(4096 / 128, 256 / 128), 256, 0, stream>>>(
            hsplit3, 3072, wcat3, 3072, mstep, nullptr, 4096, 256, 4096, 3072,
            nullptr, addcat + (size_t)t * 4096, (long)T_ * 4096);
        gru_cell3<<<(B_ * D_) / 256, 256, 0, stream>>>(mstep, gi_bf, xbuf_bf, hf, hsplit3, t);
    }

    // ================= gumbel softmax =================
    gumbel_softmax_k<<<B_ * ZL_, ZD_, 0, stream>>>(hf, out);

    // ================= decoder (fp32 — z stays exact) =================
    const float* zmat = out + (size_t)B_ * ZL_ * ZD_;
    float* xhat = out + (size_t)2 * B_ * ZL_ * ZD_;
    gemm_nt<64, 64, 16, 4, 4><<<dim3(H_ / 64, B_ / 64), 256, 0, stream>>>(
        zmat, D_, dec_w1, D_, d1, H_, B_, H_, D_, nullptr, nullptr, 0);
    hipMemsetAsync(ssum, 0, 32768, stream);
    bn_stats<<<dim3(H_ / 256, 1), 256, 0, stream>>>(d1, B_, H_, B_, ssum, ssq);
    bn_norm_f<<<(size_t)B_ * H_ / 1024, 256, 0, stream>>>(d1, d1, B_, H_,
                                                          ssum, ssq, dec_g1, dec_bt1, 1);
    gemm_nt<64, 64, 16, 4, 4><<<dim3(OBS_ / 64, B_ / 64), 256, 0, stream>>>(
        d1, H_, dec_w2, H_, xhat, OBS_, B_, OBS_, H_, nullptr, nullptr, 0);
    hipMemsetAsync(ssum, 0, 32768, stream);
    bn_stats<<<dim3(OBS_ / 256, 1), 256, 0, stream>>>(xhat, B_, OBS_, B_, ssum, ssq);
    bn_norm_f<<<(size_t)B_ * OBS_ / 1024, 256, 0, stream>>>(xhat, xhat, B_, OBS_,
                                                            ssum, ssq, dec_g2, dec_bt2, 0);
}

// Round 6
// 4411.068 us; speedup vs baseline: 3.4622x; 1.8987x over previous
//
#include <hip/hip_runtime.h>
#include <cstdint>
#include <cstddef>

// Problem constants
#define B_    256
#define T_    64
#define OBS_  4096
#define D_    1024
#define A_    8
#define H_    2048
#define ZL_   4
#define ZD_   256
#define MT_   (B_ * T_)
#define EPS_  1e-5f

typedef unsigned short u16;
typedef __attribute__((ext_vector_type(8))) short short8v;   // 8 bf16 in 4 VGPRs
typedef __attribute__((ext_vector_type(4))) float float4v;   // MFMA accumulator

__device__ __forceinline__ u16 f2bf(float f) {               // RNE f32->bf16
    uint32_t u = __float_as_uint(f);
    return (u16)((u + 0x7FFFu + ((u >> 16) & 1u)) >> 16);
}
__device__ __forceinline__ float bf2f(u16 h) {
    return __uint_as_float(((uint32_t)h) << 16);
}

// async global->LDS, 16B per lane. LDS base wave-uniform; HW writes base+lane*16.
__device__ __forceinline__ void async_cp16(const void* g, void* l) {
    __builtin_amdgcn_global_load_lds(
        (const __attribute__((address_space(1))) void*)g,
        (__attribute__((address_space(3))) void*)l, 16, 0, 0);
}

// ---------------------------------------------------------------------------
// bf16 MFMA GEMM, NT, double-buffered staging + optional K-split (blockIdx.z):
//   block z covers K range [z*ksub, z*ksub+ksub), writes Cf + z*zstride.
// C[M,N] = A[M,K] . B[N,K]^T, fp32 accum. Optional +bias[N], +Cinit(bf16).
// (bias/Cinit only valid with gridDim.z==1.)
// Tile 128x128, BK=32, 4 waves (2x2), each wave 4x4 16x16x32 fragments.
// M%128==0, N%128==0, ksub%32==0, lda/ldb/ldc %8==0.
// ---------------------------------------------------------------------------
__global__ __launch_bounds__(256)
void mfma_gemm_nt(const u16* __restrict__ A, int lda,
                  const u16* __restrict__ Bm, int ldb,
                  float* __restrict__ Cf, u16* __restrict__ Cb, int ldc,
                  int M, int N,
                  const float* __restrict__ bias,
                  const u16* __restrict__ Cinit, long ldci,
                  int ksub, long zstride)
{
    __shared__ u16 As[2][128 * 32];
    __shared__ u16 Bs[2][128 * 32];

    const int tid  = threadIdx.x;
    const int lane = tid & 63;
    const int w    = tid >> 6;         // wave 0..3
    const int wm   = w >> 1;           // wave row (0..1)
    const int wn   = w & 1;            // wave col (0..1)
    const int bm0  = blockIdx.y * 128;
    const int bn0  = blockIdx.x * 128;
    const int kb   = blockIdx.z * ksub;

    float4v acc[4][4];
#pragma unroll
    for (int i = 0; i < 4; ++i)
#pragma unroll
        for (int j = 0; j < 4; ++j)
            acc[i][j] = (float4v){0.f, 0.f, 0.f, 0.f};

    // staging: chunk q of wave w covers tile rows (w*2+q)*16 + lane/4,
    // k-slice (lane%4)*8. LDS layout As[buf][tile_row*32 + k_off].
    const int srow = lane >> 2;
    const int skel = (lane & 3) * 8;
    const int r0t  = (w * 2 + 0) * 16 + srow;
    const int r1t  = (w * 2 + 1) * 16 + srow;

    const int fr = lane & 15;          // fragment row within 16
    const int fo = (lane >> 4) * 8;    // fragment k offset (8 elems)

    auto stage = [&](int bf, int k0) {
        async_cp16(A  + (size_t)(bm0 + r0t) * lda + k0 + skel, &As[bf][(w * 2 + 0) * 512]);
        async_cp16(A  + (size_t)(bm0 + r1t) * lda + k0 + skel, &As[bf][(w * 2 + 1) * 512]);
        async_cp16(Bm + (size_t)(bn0 + r0t) * ldb + k0 + skel, &Bs[bf][(w * 2 + 0) * 512]);
        async_cp16(Bm + (size_t)(bn0 + r1t) * ldb + k0 + skel, &Bs[bf][(w * 2 + 1) * 512]);
    };

    stage(0, kb);
    __syncthreads();                 // drain prologue stage
    int cur = 0;
    for (int k0 = kb; k0 < kb + ksub; k0 += 32) {
        if (k0 + 32 < kb + ksub) stage(cur ^ 1, k0 + 32);   // in flight during compute

        short8v fa[4], fb[4];
#pragma unroll
        for (int i = 0; i < 4; ++i) {
            fa[i] = *(const short8v*)&As[cur][(wm * 64 + i * 16 + fr) * 32 + fo];
            fb[i] = *(const short8v*)&Bs[cur][(wn * 64 + i * 16 + fr) * 32 + fo];
        }
#pragma unroll
        for (int i = 0; i < 4; ++i)
#pragma unroll
            for (int j = 0; j < 4; ++j)
                acc[i][j] = __builtin_amdgcn_mfma_f32_16x16x32_bf16(fa[i], fb[j], acc[i][j], 0, 0, 0);

        __syncthreads();             // drains prefetch; buf[cur] fully consumed
        cur ^= 1;
    }

    // epilogue: C/D layout col = lane&15, row = (lane>>4)*4 + reg (m89-verified)
    float* Cfz = Cf ? Cf + (size_t)blockIdx.z * zstride : nullptr;
    const int cr = (lane >> 4) * 4;
    const int cc = lane & 15;
#pragma unroll
    for (int i = 0; i < 4; ++i) {
#pragma unroll
        for (int j = 0; j < 4; ++j) {
#pragma unroll
            for (int r = 0; r < 4; ++r) {
                const int row = bm0 + wm * 64 + i * 16 + cr + r;
                const int col = bn0 + wn * 64 + j * 16 + cc;
                float v = acc[i][j][r];
                if (bias)  v += bias[col];
                if (Cinit) v += bf2f(Cinit[(size_t)row * ldci + col]);
                if (Cfz) Cfz[(size_t)row * ldc + col] = v;
                if (Cb)  Cb[(size_t)row * ldc + col] = f2bf(v);
            }
        }
    }
}

// ---------------------------------------------------------------------------
// fp32 tiled GEMM (NT) — decoder GEMMs + exact Wpre = whh . Wje.
// ---------------------------------------------------------------------------
template <int BM, int BN, int BK, int TM, int TN>
__global__ __launch_bounds__((BM / TM) * (BN / TN))
void gemm_nt(const float* __restrict__ A, int lda,
             const float* __restrict__ Bm, int ldb,
             float* __restrict__ C, int ldc,
             int M, int N, int K,
             const float* __restrict__ bias,
             const float* __restrict__ Cinit, int ldci)
{
    constexpr int NT  = (BM / TM) * (BN / TN);
    constexpr int TNX = BN / TN;
    __shared__ float As[BK][BM];
    __shared__ float Bs[BK][BN];
    const int tid = threadIdx.x;
    const int tn_idx = tid % TNX;
    const int tm_idx = tid / TNX;
    const int bm0 = blockIdx.y * BM;
    const int bn0 = blockIdx.x * BN;

    float acc[TM][TN];
#pragma unroll
    for (int i = 0; i < TM; ++i)
#pragma unroll
        for (int j = 0; j < TN; ++j) acc[i][j] = 0.f;

    for (int k0 = 0; k0 < K; k0 += BK) {
#pragma unroll
        for (int l = tid; l < BM * BK / 4; l += NT) {
            const int row = l / (BK / 4);
            const int kq  = l % (BK / 4);
            const float4 v = *(const float4*)&A[(size_t)(bm0 + row) * lda + k0 + kq * 4];
            As[kq * 4 + 0][row] = v.x; As[kq * 4 + 1][row] = v.y;
            As[kq * 4 + 2][row] = v.z; As[kq * 4 + 3][row] = v.w;
        }
#pragma unroll
        for (int l = tid; l < BN * BK / 4; l += NT) {
            const int row = l / (BK / 4);
            const int kq  = l % (BK / 4);
            const float4 v = *(const float4*)&Bm[(size_t)(bn0 + row) * ldb + k0 + kq * 4];
            Bs[kq * 4 + 0][row] = v.x; Bs[kq * 4 + 1][row] = v.y;
            Bs[kq * 4 + 2][row] = v.z; Bs[kq * 4 + 3][row] = v.w;
        }
        __syncthreads();
#pragma unroll
        for (int kk = 0; kk < BK; ++kk) {
            float a[TM], b[TN];
#pragma unroll
            for (int i = 0; i < TM; i += 4)
                *(float4*)&a[i] = *(const float4*)&As[kk][tm_idx * TM + i];
#pragma unroll
            for (int j = 0; j < TN; j += 4)
                *(float4*)&b[j] = *(const float4*)&Bs[kk][tn_idx * TN + j];
#pragma unroll
            for (int i = 0; i < TM; ++i)
#pragma unroll
                for (int j = 0; j < TN; ++j)
                    acc[i][j] = fmaf(a[i], b[j], acc[i][j]);
        }
        __syncthreads();
    }
#pragma unroll
    for (int i = 0; i < TM; ++i) {
        const int r = bm0 + tm_idx * TM + i;
#pragma unroll
        for (int j = 0; j < TN; j += 4) {
            const int c = bn0 + tn_idx * TN + j;
            float4 v = *(float4*)&acc[i][j];
            if (bias) { v.x += bias[c]; v.y += bias[c+1]; v.z += bias[c+2]; v.w += bias[c+3]; }
            if (Cinit) {
                const float4 ci = *(const float4*)&Cinit[(size_t)r * ldci + c];
                v.x += ci.x; v.y += ci.y; v.z += ci.z; v.w += ci.w;
            }
            *(float4*)&C[(size_t)r * ldc + c] = v;
        }
    }
}

// ---------------------------------------------------------------------------
// fp32 -> bf16 cast, 2D (8 elems/thread). C%8==0.
// ---------------------------------------------------------------------------
__global__ void cast2d_k(const float* __restrict__ src, int sld,
                         u16* __restrict__ dst, int dld, long total, int C)
{
    long i = ((long)blockIdx.x * blockDim.x + threadIdx.x) * 8;
    if (i >= total) return;
    const int r = (int)(i / C);
    const int c = (int)(i % C);
    const float* s = src + (size_t)r * sld + c;
    const float4 a = *(const float4*)s;
    const float4 b = *(const float4*)(s + 4);
    uint4 o;
    o.x = (uint32_t)f2bf(a.x) | ((uint32_t)f2bf(a.y) << 16);
    o.y = (uint32_t)f2bf(a.z) | ((uint32_t)f2bf(a.w) << 16);
    o.z = (uint32_t)f2bf(b.x) | ((uint32_t)f2bf(b.y) << 16);
    o.w = (uint32_t)f2bf(b.z) | ((uint32_t)f2bf(b.w) << 16);
    *(uint4*)&dst[(size_t)r * dld + c] = o;
}

// f32 transpose: dst[c][r] = src[r][c]
__global__ void trans_f32_k(const float* __restrict__ src, int sld,
                            float* __restrict__ dst, int dld)
{
    __shared__ float t[32][33];
    const int c0 = blockIdx.x * 32, r0 = blockIdx.y * 32;
    for (int dy = threadIdx.y; dy < 32; dy += 8)
        t[dy][threadIdx.x] = src[(size_t)(r0 + dy) * sld + c0 + threadIdx.x];
    __syncthreads();
    for (int dy = threadIdx.y; dy < 32; dy += 8)
        dst[(size_t)(c0 + dy) * dld + r0 + threadIdx.x] = t[threadIdx.x][dy];
}

// split-cast into scan weight triple: dst row r gets [hi | hi | lo] (1024 each)
__global__ void cast_split3_k(const float* __restrict__ src, int sld,
                              u16* __restrict__ dst, long total)
{
    long idx = (long)blockIdx.x * blockDim.x + threadIdx.x;
    if (idx >= total) return;
    const int r = (int)(idx >> 10);
    const int c = (int)(idx & 1023);
    const float w = src[(size_t)r * sld + c];
    const u16 hi = f2bf(w);
    const u16 lo = f2bf(w - bf2f(hi));
    u16* dp = dst + (size_t)r * 3072;
    dp[c] = hi; dp[1024 + c] = hi; dp[2048 + c] = lo;
}

// ---------------------------------------------------------------------------
// BatchNorm stats + normalize variants
// ---------------------------------------------------------------------------
__global__ void bn_stats(const float* __restrict__ X, int M, int N, int chunk,
                         float* __restrict__ sum, float* __restrict__ sumsq)
{
    const int c  = blockIdx.x * blockDim.x + threadIdx.x;
    const int r0 = blockIdx.y * chunk;
    const int r1 = min(M, r0 + chunk);
    float s = 0.f, ss = 0.f;
    for (int r = r0; r < r1; ++r) {
        const float v = X[(size_t)r * N + c];
        s += v; ss = fmaf(v, v, ss);
    }
    atomicAdd(&sum[c], s);
    atomicAdd(&sumsq[c], ss);
}

__global__ void bn_stats_bf(const u16* __restrict__ X, int M, int N, int chunk,
                            float* __restrict__ sum, float* __restrict__ sumsq)
{
    const int c  = blockIdx.x * blockDim.x + threadIdx.x;
    const int r0 = blockIdx.y * chunk;
    const int r1 = min(M, r0 + chunk);
    float s = 0.f, ss = 0.f;
    for (int r = r0; r < r1; ++r) {
        const float v = bf2f(X[(size_t)r * N + c]);
        s += v; ss = fmaf(v, v, ss);
    }
    atomicAdd(&sum[c], s);
    atomicAdd(&sumsq[c], ss);
}

// bf16 in -> bf16 out (src may alias dst); 8 elems/thread, N%8==0
__global__ void bn_norm_bf(const u16* __restrict__ src, u16* __restrict__ dst,
                           int M, int N,
                           const float* __restrict__ sum, const float* __restrict__ sumsq,
                           const float* __restrict__ gamma, const float* __restrict__ beta,
                           int relu)
{
    const size_t idx = (size_t)blockIdx.x * blockDim.x + threadIdx.x;
    const size_t e0  = idx * 8;
    const int c0 = (int)(e0 % N);
    const uint4 v = *(const uint4*)&src[e0];
    const u16* pv = (const u16*)&v;
    const float invM = 1.f / (float)M;
    u16 o[8];
#pragma unroll
    for (int j = 0; j < 8; ++j) {
        const int c = c0 + j;
        const float m   = sum[c] * invM;
        const float var = sumsq[c] * invM - m * m;
        float y = gamma[c] * (bf2f(pv[j]) - m) * rsqrtf(var + EPS_) + beta[c];
        if (relu) y = fmaxf(y, 0.f);
        o[j] = f2bf(y);
    }
    *(uint4*)&dst[e0] = *(uint4*)o;
}

// f32 in -> f32 out (decoder)
__global__ void bn_norm_f(const float* __restrict__ src, float* __restrict__ dst,
                          int M, int N,
                          const float* __restrict__ sum, const float* __restrict__ sumsq,
                          const float* __restrict__ gamma, const float* __restrict__ beta,
                          int relu)
{
    const size_t idx = (size_t)blockIdx.x * blockDim.x + threadIdx.x;
    const size_t e0  = idx * 4;
    const int c0 = (int)(e0 % N);
    const float4 v = *(const float4*)&src[e0];
    const float invM = 1.f / (float)M;
    float o[4] = {v.x, v.y, v.z, v.w};
#pragma unroll
    for (int j = 0; j < 4; ++j) {
        const int c = c0 + j;
        const float m   = sum[c] * invM;
        const float var = sumsq[c] * invM - m * m;
        float y = gamma[c] * (o[j] - m) * rsqrtf(var + EPS_) + beta[c];
        if (relu) y = fmaxf(y, 0.f);
        o[j] = y;
    }
    float4 w = {o[0], o[1], o[2], o[3]};
    *(float4*)&dst[e0] = w;
}

// ---------------------------------------------------------------------------
// ap into addcat cols 0..1023 (row stride 4096)
// ---------------------------------------------------------------------------
__global__ void apart_k(const float* __restrict__ act,
                        const float* __restrict__ je_w,
                        const float* __restrict__ je_b,
                        u16* __restrict__ addcat)
{
    const size_t idx = (size_t)blockIdx.x * blockDim.x + threadIdx.x;
    const int r = (int)(idx >> 10);
    const int d = (int)(idx & 1023);
    float s = je_b[d];
    const float* wa = je_w + (size_t)d * (D_ + A_) + D_;
    const float* a  = act + (size_t)r * A_;
#pragma unroll
    for (int k = 0; k < A_; ++k) s = fmaf(a[k], wa[k], s);
    addcat[(size_t)r * 4096 + d] = f2bf(s);
}

// ---------------------------------------------------------------------------
// GRU cell + residual, K-split variant: sums 4 f32 partials + addcat_t.
// partial P [4][256][4096]; cols: [hj | ghr | ghz | ghn].
// ---------------------------------------------------------------------------
__global__ void gru_cell4(const float* __restrict__ P,
                          const u16* __restrict__ addcat,  // [MT,4096]
                          const u16* __restrict__ gi,      // [MT,3072]
                          const u16* __restrict__ x,       // [MT,1024]
                          float* __restrict__ hf,          // [256,1024]
                          u16* __restrict__ hsplit3,       // [256,3072]
                          int t)
{
    const int idx = blockIdx.x * blockDim.x + threadIdx.x; // [0, 262144)
    const int b = idx >> 10;
    const int d = idx & 1023;
    const size_t r = (size_t)b * T_ + t;
    const size_t pb = (size_t)b * 4096;
    const u16* ac = addcat + r * 4096;

    float s[4];
#pragma unroll
    for (int g = 0; g < 4; ++g) {
        const int col = g * 1024 + d;
        float v = bf2f(ac[col]);
#pragma unroll
        for (int ks = 0; ks < 4; ++ks)
            v += P[(size_t)ks * (256 * 4096) + pb + col];
        s[g] = v;
    }
    const float hj = s[0], ghr = s[1], ghz = s[2], ghn = s[3];
    const u16* gp = gi + r * 3072;
    const float gir = bf2f(gp[d]), giz = bf2f(gp[1024 + d]), gin = bf2f(gp[2048 + d]);

    const float rr = 1.f / (1.f + expf(-(gir + ghr)));
    const float zz = 1.f / (1.f + expf(-(giz + ghz)));
    const float nn = tanhf(fmaf(rr, ghn, gin));
    const float h  = (1.f - zz) * nn + zz * hj + bf2f(x[r * 1024 + d]);

    hf[idx] = h;
    const u16 hi = f2bf(h);
    const u16 lo = f2bf(h - bf2f(hi));
    u16* hp = hsplit3 + (size_t)b * 3072;
    hp[d] = hi; hp[1024 + d] = lo; hp[2048 + d] = hi;
}

// ---------------------------------------------------------------------------
// JAX threefry2x32 (key=(0,42)), partitionable scheme — validated round 3.
// ---------------------------------------------------------------------------
__device__ __forceinline__ uint32_t rotl32(uint32_t x, int d)
{
    return (x << d) | (x >> (32 - d));
}

__device__ inline void threefry2x32(uint32_t k0, uint32_t k1,
                                    uint32_t& x0, uint32_t& x1)
{
    const uint32_t ks0 = k0, ks1 = k1, ks2 = k0 ^ k1 ^ 0x1BD11BDAu;
    x0 += ks0; x1 += ks1;
    const int ra[4] = {13, 15, 26, 6};
    const int rb[4] = {17, 29, 16, 24};
#pragma unroll
    for (int i = 0; i < 4; ++i) { x0 += x1; x1 = rotl32(x1, ra[i]); x1 ^= x0; }
    x0 += ks1; x1 += ks2 + 1u;
#pragma unroll
    for (int i = 0; i < 4; ++i) { x0 += x1; x1 = rotl32(x1, rb[i]); x1 ^= x0; }
    x0 += ks2; x1 += ks0 + 2u;
#pragma unroll
    for (int i = 0; i < 4; ++i) { x0 += x1; x1 = rotl32(x1, ra[i]); x1 ^= x0; }
    x0 += ks0; x1 += ks1 + 3u;
#pragma unroll
    for (int i = 0; i < 4; ++i) { x0 += x1; x1 = rotl32(x1, rb[i]); x1 ^= x0; }
    x0 += ks1; x1 += ks2 + 4u;
#pragma unroll
    for (int i = 0; i < 4; ++i) { x0 += x1; x1 = rotl32(x1, ra[i]); x1 ^= x0; }
    x0 += ks2; x1 += ks0 + 5u;
}

__global__ void gumbel_softmax_k(const float* __restrict__ h, float* __restrict__ out)
{
    const int row = blockIdx.x;
    const int tid = threadIdx.x;
    const int i   = row * ZD_ + tid;
    const int lane = tid & 63;
    const int wave = tid >> 6;

    const float logit = h[i];

    uint32_t x0 = 0u, x1 = (uint32_t)i;
    threefry2x32(0u, 42u, x0, x1);
    const uint32_t bits = x0 ^ x1;

    const float tiny = 1.17549435e-38f;
    float f = __uint_as_float((bits >> 9) | 0x3f800000u) - 1.0f;
    f = f + tiny;
    f = fmaxf(f, tiny);
    const float g = -logf(-logf(f));

    const float val = (logit + g) / 1.0f;

    __shared__ float red[4];
    float m = val;
#pragma unroll
    for (int o = 1; o < 64; o <<= 1) m = fmaxf(m, __shfl_xor(m, o, 64));
    if (lane == 0) red[wave] = m;
    __syncthreads();
    const float mm = fmaxf(fmaxf(red[0], red[1]), fmaxf(red[2], red[3]));
    __syncthreads();

    const float e = expf(val - mm);
    float s = e;
#pragma unroll
    for (int o = 1; o < 64; o <<= 1) s += __shfl_xor(s, o, 64);
    if (lane == 0) red[wave] = s;
    __syncthreads();
    const float ssum = red[0] + red[1] + red[2] + red[3];

    out[i] = logit;
    out[B_ * ZL_ * ZD_ + i] = e / ssum;
}

// ---------------------------------------------------------------------------
// Host-side launch
// ---------------------------------------------------------------------------
extern "C" void kernel_launch(void* const* d_in, const int* in_sizes, int n_in,
                              void* d_out, int out_size, void* d_ws, size_t ws_size,
                              hipStream_t stream)
{
    const float* obs      = (const float*)d_in[0];
    const float* actions  = (const float*)d_in[1];
    const float* enc_w1   = (const float*)d_in[2];
    const float* enc_g1   = (const float*)d_in[4];
    const float* enc_bt1  = (const float*)d_in[5];
    const float* enc_w2   = (const float*)d_in[6];
    const float* enc_g2   = (const float*)d_in[8];
    const float* enc_bt2  = (const float*)d_in[9];
    const float* je_w     = (const float*)d_in[10];
    const float* je_b     = (const float*)d_in[11];
    const float* gru_wih  = (const float*)d_in[12];
    const float* gru_bih  = (const float*)d_in[13];
    const float* gru_whh  = (const float*)d_in[14];
    const float* gru_bhh  = (const float*)d_in[15];
    const float* dec_w1   = (const float*)d_in[16];
    const float* dec_g1   = (const float*)d_in[18];
    const float* dec_bt1  = (const float*)d_in[19];
    const float* dec_w2   = (const float*)d_in[20];
    const float* dec_g2   = (const float*)d_in[22];
    const float* dec_bt2  = (const float*)d_in[23];

    float* out = (float*)d_out;

    // ---- workspace layout (~327 MB; round-5 proven envelope) ----
    char* P = (char*)d_ws;
    // slab0 [0, 128MB): obs_bf -> addcat [16384,4096]bf16
    u16* obs_bf = (u16*)P;
    u16* addcat = (u16*)P;
    // slab1 [128, 224MB): c2b [16384,1024]bf16 -> gi_bf [16384,3072]bf16
    u16* c2b   = (u16*)(P + 134217728);
    u16* gi_bf = (u16*)(P + 134217728);
    // slab2 [224, 288MB): c1b (64MB, dead after enc2) -> overlays below
    char* slab2 = P + 234881024;
    u16*   c1b      = (u16*)slab2;                    // [0,64MB) enc1 out
    u16*   xbuf_bf  = (u16*)slab2;                    // [0,32MB)  x bf16
    float* partials = (float*)(slab2 + 33554432);     // [32,48MB) [4][256][4096] f32
    float* hf       = (float*)(slab2 + 50331648);     // [48,49MB) [256,1024] f32
    float* d1       = (float*)(slab2 + 51380224);     // [49,51MB) [256,2048] f32
    float* wpreF    = (float*)(slab2 + 54525952);     // [52,64MB) [3072,1024] f32
    // weights [288MB, ...): w1b/w2b/wihb pool overlaid by wcat3 after gi
    char* wp = P + 301989888;
    u16*  w1b   = (u16*)wp;                 // 16 MB  [2048,4096]
    u16*  w2b   = (u16*)(wp + 16777216);    // 4 MB   [1024,2048]
    u16*  wihb  = (u16*)(wp + 20971520);    // 6 MB   [3072,1024]
    u16*  wcat3 = (u16*)wp;                 // 24 MB  [4096,3072] overlays w1b/w2b/wihb
    u16*  whhb  = (u16*)(wp + 27262976);    // 6 MB   [3072,1024]
    float* wjetf = (float*)(wp + 33554432); // 4 MB   [1024,1024] f32 (Wje^T)
    float* ssum  = (float*)(wp + 37748736); // 16 KB
    float* ssq   = (float*)(wp + 37765120); // 16 KB
    u16*  hsplit3 = (u16*)(wp + 37781504);  // 1.5 MB [256,3072]

    // ================= casts =================
    cast2d_k<<<32768, 256, 0, stream>>>(obs,     4096, obs_bf, 4096, (long)MT_ * OBS_, OBS_);
    cast2d_k<<<4096,  256, 0, stream>>>(enc_w1,  4096, w1b,    4096, (long)H_ * OBS_,  OBS_);
    cast2d_k<<<1024,  256, 0, stream>>>(enc_w2,  2048, w2b,    2048, (long)D_ * H_,    H_);
    cast2d_k<<<1536,  256, 0, stream>>>(gru_wih, 1024, wihb,   1024, (long)3 * D_ * D_, D_);
    cast2d_k<<<1536,  256, 0, stream>>>(gru_whh, 1024, whhb,   1024, (long)3 * D_ * D_, D_);
    trans_f32_k<<<dim3(32, 32), dim3(32, 8), 0, stream>>>(je_w, D_ + A_, wjetf, D_);

    // ================= encoder (bf16 MFMA; BN stats on bf16 pre-act) ========
    mfma_gemm_nt<<<dim3(H_ / 128, MT_ / 128), 256, 0, stream>>>(
        obs_bf, OBS_, w1b, OBS_, nullptr, c1b, H_, MT_, H_,
        nullptr, nullptr, 0, OBS_, 0L);
    hipMemsetAsync(ssum, 0, 32768, stream);
    bn_stats_bf<<<dim3(H_ / 256, MT_ / 512), 256, 0, stream>>>(c1b, MT_, H_, 512, ssum, ssq);
    bn_norm_bf<<<(size_t)MT_ * H_ / 2048, 256, 0, stream>>>(c1b, c1b, MT_, H_,
                                                            ssum, ssq, enc_g1, enc_bt1, 1);
    mfma_gemm_nt<<<dim3(D_ / 128, MT_ / 128), 256, 0, stream>>>(
        c1b, H_, w2b, H_, nullptr, c2b, D_, MT_, D_,
        nullptr, nullptr, 0, H_, 0L);
    hipMemsetAsync(ssum, 0, 32768, stream);
    bn_stats_bf<<<dim3(D_ / 256, MT_ / 512), 256, 0, stream>>>(c2b, MT_, D_, 512, ssum, ssq);
    bn_norm_bf<<<(size_t)MT_ * D_ / 2048, 256, 0, stream>>>(c2b, xbuf_bf, MT_, D_,
                                                            ssum, ssq, enc_g2, enc_bt2, 0);

    // ================= gi (scan-invariant input gates) =================
    mfma_gemm_nt<<<dim3(3 * D_ / 128, MT_ / 128), 256, 0, stream>>>(
        xbuf_bf, D_, wihb, D_, nullptr, gi_bf, 3 * D_, MT_, 3 * D_,
        gru_bih, nullptr, 0, D_, 0L);

    // ================= scan prep =================
    apart_k<<<(size_t)MT_ * D_ / 256, 256, 0, stream>>>(actions, je_w, je_b, addcat);
    mfma_gemm_nt<<<dim3(3 * D_ / 128, MT_ / 128), 256, 0, stream>>>(
        addcat, 4096, whhb, D_, nullptr, addcat + 1024, 4096, MT_, 3 * D_,
        gru_bhh, nullptr, 0, D_, 0L);
    gemm_nt<64, 64, 16, 4, 4><<<dim3(D_ / 64, 3 * D_ / 64), 256, 0, stream>>>(
        gru_whh, D_, wjetf, D_, wpreF, D_, 3 * D_, D_, D_, nullptr, nullptr, 0);
    cast_split3_k<<<4096, 256, 0, stream>>>(je_w, D_ + A_, wcat3, (long)D_ * D_);
    cast_split3_k<<<12288, 256, 0, stream>>>(wpreF, D_, wcat3 + (size_t)1024 * 3072,
                                             (long)3 * D_ * D_);

    // ================= recurrent scan (K-split x4 + fused sum in cell) ======
    hipMemsetAsync(hsplit3, 0, (size_t)B_ * 3072 * 2, stream);
    for (int t = 0; t < T_; ++t) {
        // partials[z] = [h_hi|h_lo|h_hi] @ wcat3[:, z*768:(z+1)*768]^T
        mfma_gemm_nt<<<dim3(4096 / 128, 256 / 128, 4), 256, 0, stream>>>(
            hsplit3, 3072, wcat3, 3072, partials, nullptr, 4096, 256, 4096,
            nullptr, nullptr, 0, 768, (long)256 * 4096);
        gru_cell4<<<(B_ * D_) / 256, 256, 0, stream>>>(
            partials, addcat, gi_bf, xbuf_bf, hf, hsplit3, t);
    }

    // ================= gumbel softmax =================
    gumbel_softmax_k<<<B_ * ZL_, ZD_, 0, stream>>>(hf, out);

    // ================= decoder (fp32 — z stays exact) =================
    const float* zmat = out + (size_t)B_ * ZL_ * ZD_;
    float* xhat = out + (size_t)2 * B_ * ZL_ * ZD_;
    gemm_nt<64, 64, 16, 4, 4><<<dim3(H_ / 64, B_ / 64), 256, 0, stream>>>(
        zmat, D_, dec_w1, D_, d1, H_, B_, H_, D_, nullptr, nullptr, 0);
    hipMemsetAsync(ssum, 0, 32768, stream);
    bn_stats<<<dim3(H_ / 256, 1), 256, 0, stream>>>(d1, B_, H_, B_, ssum, ssq);
    bn_norm_f<<<(size_t)B_ * H_ / 1024, 256, 0, stream>>>(d1, d1, B_, H_,
                                                          ssum, ssq, dec_g1, dec_bt1, 1);
    gemm_nt<64, 64, 16, 4, 4><<<dim3(OBS_ / 64, B_ / 64), 256, 0, stream>>>(
        d1, H_, dec_w2, H_, xhat, OBS_, B_, OBS_, H_, nullptr, nullptr, 0);
    hipMemsetAsync(ssum, 0, 32768, stream);
    bn_stats<<<dim3(OBS_ / 256, 1), 256, 0, stream>>>(xhat, B_, OBS_, B_, ssum, ssq);
    bn_norm_f<<<(size_t)B_ * OBS_ / 1024, 256, 0, stream>>>(xhat, xhat, B_, OBS_,
                                                            ssum, ssq, dec_g2, dec_bt2, 0);
}